// Round 6
// baseline (292.898 us; speedup 1.0000x reference)
//
#include <hip/hip_runtime.h>
#include <math.h>

namespace {
constexpr int B_  = 8;
constexpr int U_  = 16384;
constexpr int S_  = 4096;
constexpr int E_  = 128;
constexpr int NTOK  = B_ * U_;   // 131072
constexpr int NCELL = B_ * S_;   // 32768
constexpr int FUSED_GRID = 512;  // persistent blocks (2/CU at 1024 thr)
constexpr int SWZ3 = 3 * 16384;  // Wk,Wv,Wo swizzle elements
}

typedef __attribute__((ext_vector_type(8))) short bf16x8;
typedef __attribute__((ext_vector_type(4))) float f32x4;

__device__ inline unsigned short bf16rne(float x) {
  unsigned u = __float_as_uint(x);
  u = u + 0x7fffu + ((u >> 16) & 1u);
  return (unsigned short)(u >> 16);
}

__device__ inline bf16x8 pack8(float4 a, float4 b) {
  bf16x8 r;
  r[0] = (short)bf16rne(a.x); r[1] = (short)bf16rne(a.y);
  r[2] = (short)bf16rne(a.z); r[3] = (short)bf16rne(a.w);
  r[4] = (short)bf16rne(b.x); r[5] = (short)bf16rne(b.y);
  r[6] = (short)bf16rne(b.z); r[7] = (short)bf16rne(b.w);
  return r;
}

// ------------------------------------------------------------------
// L1: one wide launch.
//  blocks 0..15  : qproj (self-swizzles Wq fp32 -> bf16 LDS, then MFMA)
//  blocks 16..47 : grid-stride { swizzle Wk/Wv/Wo -> Wsw, bucketize+count }
//  (cnt must be zeroed beforehand via hipMemsetAsync)
// ------------------------------------------------------------------
__global__ __launch_bounds__(1024, 4) void setup_kernel(
    const float* __restrict__ Wq, const float* __restrict__ Wk,
    const float* __restrict__ Wv, const float* __restrict__ Wo,
    const float* __restrict__ latents, const float* __restrict__ xc_off,
    unsigned short* __restrict__ Wsw, float* __restrict__ Qp,
    int* __restrict__ seg_arr, int* __restrict__ cnt) {
  const int tid = threadIdx.x;

  if (blockIdx.x < 16) {
    // ---------- qproj: Qp = 0.25 * latents @ Wq, Qp[s][d*8+h] ----------
    __shared__ __align__(16) unsigned short wq[16384];
    for (int i = tid; i < 16384; i += 1024) {
      const int k = i >> 7, n = i & 127;
      wq[(((k >> 3) * 128 + n) << 3) + (k & 7)] = bf16rne(Wq[i]);
    }
    __syncthreads();

    const int wave = tid >> 6, lane = tid & 63;
    const int c = lane & 15, g = lane >> 4;
    const int t0w = blockIdx.x * 256 + wave * 16;

    f32x4 acc[8];
#pragma unroll
    for (int i = 0; i < 8; ++i) acc[i] = {0.f, 0.f, 0.f, 0.f};

    const float* arow = latents + (size_t)(t0w + c) * E_ + g * 8;
    const bf16x8* bq = (const bf16x8*)wq;
#pragma unroll
    for (int ks = 0; ks < 4; ++ks) {
      float4 a0 = *(const float4*)(arow + ks * 32);
      float4 a1 = *(const float4*)(arow + ks * 32 + 4);
      bf16x8 af = pack8(a0, a1);
      const int bo = (ks * 4 + g) * 128 + c;
#pragma unroll
      for (int nt = 0; nt < 8; ++nt)
        acc[nt] = __builtin_amdgcn_mfma_f32_16x16x32_bf16(af, bq[bo + nt * 16], acc[nt], 0, 0, 0);
    }
#pragma unroll
    for (int nt = 0; nt < 8; ++nt)
#pragma unroll
      for (int r = 0; r < 4; ++r)
        Qp[(size_t)(t0w + g * 4 + r) * E_ + c * 8 + nt] = acc[nt][r] * 0.25f;
  } else {
    // ---------- elementwise: swizzle 3 weights + bucketize ----------
    const int base = (blockIdx.x - 16) * 1024 + tid;
    const int stride = 32 * 1024;
    for (int i = base; i < SWZ3 + NTOK; i += stride) {
      if (i < SWZ3) {
        const int w = i >> 14, e = i & 16383;
        const int k = e >> 7, n = e & 127;
        const float* src = (w == 0) ? Wk : (w == 1) ? Wv : Wo;
        Wsw[w * 16384 + (((k >> 3) * 128 + n) << 3) + (k & 7)] = bf16rne(src[e]);
      } else {
        const int tok = i - SWZ3;
        const int b = tok >> 14;
        // EXACT replication of reference fp32 bucketize math
        const float sp = 1.0f / 63.0f;
        const float half = sp * 0.5f;
        const float x0 = xc_off[(size_t)tok * 2 + 0];
        const float x1 = xc_off[(size_t)tok * 2 + 1];
        float n0 = floorf((x0 - 0.0f + half) / sp);
        float n1 = floorf((x1 - 0.0f + half) / sp);
        n0 = fminf(fmaxf(n0, 0.0f), 63.0f);
        n1 = fminf(fmaxf(n1, 0.0f), 63.0f);
        const int seg = b * S_ + (int)(n0 * 64.0f + n1);
        seg_arr[tok] = seg;
        atomicAdd(&cnt[seg], 1);
      }
    }
  }
}

// ------------------------------------------------------------------
// L2: exclusive scan of 32K counts (single block)
// ------------------------------------------------------------------
__global__ __launch_bounds__(1024) void scan_kernel(
    const int* __restrict__ cnt, int* __restrict__ offs, int* __restrict__ cursor) {
  __shared__ int sh[1024];
  const int tid = threadIdx.x;
  const int base = tid * 32;
  int local[32];
  int tot = 0;
#pragma unroll
  for (int i = 0; i < 32; ++i) { local[i] = cnt[base + i]; tot += local[i]; }
  sh[tid] = tot;
  __syncthreads();
  for (int ofs = 1; ofs < 1024; ofs <<= 1) {
    int v = (tid >= ofs) ? sh[tid - ofs] : 0;
    __syncthreads();
    sh[tid] += v;
    __syncthreads();
  }
  int run = sh[tid] - tot;
#pragma unroll
  for (int i = 0; i < 32; ++i) {
    offs[base + i] = run;
    cursor[base + i] = run;
    run += local[i];
  }
  if (tid == 1023) offs[NCELL] = run;
}

// ------------------------------------------------------------------
// L3: scatter token ids into sorted order
// ------------------------------------------------------------------
__global__ __launch_bounds__(256) void scatter_ids(
    const int* __restrict__ seg_arr, int* __restrict__ cursor,
    int* __restrict__ sorted) {
  const int tok = blockIdx.x * 256 + threadIdx.x;
  const int seg = seg_arr[tok];
  const int r = atomicAdd(&cursor[seg], 1);
  sorted[r] = tok;
}

// ------------------------------------------------------------------
// L4: fused per-cell kernel (1024 thr = 16 waves, 2 blocks/CU).
// One wave owns one cell; per-head K->w->V fusion; zero scatter atomics.
// ------------------------------------------------------------------
__global__ __launch_bounds__(1024, 8) void fused_cells(
    const float* __restrict__ zc_off, const float* __restrict__ zc_on,
    const float* __restrict__ fake, const int* __restrict__ ignore_flag,
    const unsigned short* __restrict__ Wk_sw, const unsigned short* __restrict__ Wv_sw,
    const float* __restrict__ Qp, const int* __restrict__ offs,
    const int* __restrict__ sorted, float* __restrict__ out) {
  __shared__ __align__(16) unsigned short wk[16384];
  __shared__ __align__(16) unsigned short wv[16384];
  const int tid = threadIdx.x;
  {
    const uint4* sk = (const uint4*)Wk_sw;
    const uint4* sv = (const uint4*)Wv_sw;
    uint4* dk = (uint4*)wk; uint4* dv = (uint4*)wv;
#pragma unroll
    for (int i = 0; i < 2; ++i) {
      dk[i * 1024 + tid] = sk[i * 1024 + tid];
      dv[i * 1024 + tid] = sv[i * 1024 + tid];
    }
  }
  const int ign = *ignore_flag;
  __syncthreads();

  const int wave = tid >> 6, lane = tid & 63;
  const int c = lane & 15, g = lane >> 4;
  const bf16x8* bk = (const bf16x8*)wk;
  const bf16x8* bv = (const bf16x8*)wv;

  for (int grp = blockIdx.x; grp < NCELL / 16; grp += FUSED_GRID) {
    const int cell = grp * 16 + wave;
    const int s = cell & (S_ - 1);
    const int base = offs[cell];
    const int n_off = offs[cell + 1] - base;
    const float* qrow = Qp + (size_t)s * E_ + c * 8;   // qrow[h] = q[h*16+c]

    float num_acc[8], den_acc[8];
#pragma unroll
    for (int i = 0; i < 8; ++i) { num_acc[i] = 0.f; den_acc[i] = 0.f; }

    const int chunks = (n_off + 16) >> 4;

    for (int ch = 0; ch < chunks; ++ch) {
      const int idx = ch * 16 + c;
      const float* arow;
      if (idx < n_off)       arow = zc_off + (size_t)sorted[base + idx] * E_;
      else if (idx == n_off) arow = ign ? fake : (zc_on + (size_t)cell * E_);
      else                   arow = zc_on;   // pad: weight forced to 0
      arow += g * 8;

      bf16x8 af[4];
#pragma unroll
      for (int ks = 0; ks < 4; ++ks) {
        float4 a0 = *(const float4*)(arow + ks * 32);
        float4 a1 = *(const float4*)(arow + ks * 32 + 4);
        af[ks] = pack8(a0, a1);
      }

#pragma unroll 2
      for (int h = 0; h < 8; ++h) {
        const int bo = g * 128 + c + h * 16;
        f32x4 aK = {0.f, 0.f, 0.f, 0.f};
#pragma unroll
        for (int ks = 0; ks < 4; ++ks)
          aK = __builtin_amdgcn_mfma_f32_16x16x32_bf16(af[ks], bk[bo + ks * 512], aK, 0, 0, 0);

        const float qv = qrow[h];
        float w[4];
#pragma unroll
        for (int r = 0; r < 4; ++r) {
          float p = aK[r] * qv;
          p += __shfl_xor(p, 1, 64); p += __shfl_xor(p, 2, 64);
          p += __shfl_xor(p, 4, 64); p += __shfl_xor(p, 8, 64);
          const int tr = ch * 16 + g * 4 + r;
          w[r] = (tr <= n_off) ? __expf(p) : 0.f;
        }

        f32x4 aV = {0.f, 0.f, 0.f, 0.f};
#pragma unroll
        for (int ks = 0; ks < 4; ++ks)
          aV = __builtin_amdgcn_mfma_f32_16x16x32_bf16(af[ks], bv[bo + ks * 512], aV, 0, 0, 0);

        float sv = 0.f, sd = 0.f;
#pragma unroll
        for (int r = 0; r < 4; ++r) { sv = fmaf(w[r], aV[r], sv); sd += w[r]; }
        num_acc[h] += sv;
        den_acc[h] += sd;
      }
    }

#pragma unroll
    for (int i = 0; i < 8; ++i) {
      num_acc[i] += __shfl_xor(num_acc[i], 16, 64);
      num_acc[i] += __shfl_xor(num_acc[i], 32, 64);
      den_acc[i] += __shfl_xor(den_acc[i], 16, 64);
      den_acc[i] += __shfl_xor(den_acc[i], 32, 64);
    }
#pragma unroll
    for (int b = 0; b < 2; ++b) {
      const int nt = 2 * g + b;
      out[(size_t)cell * E_ + nt * 16 + c] = num_acc[nt] / den_acc[nt];
    }
  }
}

// ------------------------------------------------------------------
// L5: finalize in-place: out = out @ Wo   (out already normalized)
// ------------------------------------------------------------------
__global__ __launch_bounds__(512, 4) void finalize_mfma(
    const unsigned short* __restrict__ Wo_sw, float* __restrict__ out) {
  __shared__ __align__(16) unsigned short wo[16384];
  const int tid = threadIdx.x;
  {
    const uint4* s = (const uint4*)Wo_sw;
    uint4* d = (uint4*)wo;
#pragma unroll
    for (int i = 0; i < 4; ++i) d[i * 512 + tid] = s[i * 512 + tid];
  }
  __syncthreads();

  const int wave = tid >> 6, lane = tid & 63;
  const int c = lane & 15, g = lane >> 4;
  const int t0w = blockIdx.x * 128 + wave * 16;

  f32x4 acc[8];
#pragma unroll
  for (int i = 0; i < 8; ++i) acc[i] = {0.f, 0.f, 0.f, 0.f};

  const float* nrow = out + (size_t)(t0w + c) * E_ + g * 8;
  const bf16x8* bo_ = (const bf16x8*)wo;
#pragma unroll
  for (int ks = 0; ks < 4; ++ks) {
    float4 a0 = *(const float4*)(nrow + ks * 32);
    float4 a1 = *(const float4*)(nrow + ks * 32 + 4);
    bf16x8 af = pack8(a0, a1);
    const int bofs = (ks * 4 + g) * 128 + c;
#pragma unroll
    for (int nt = 0; nt < 8; ++nt)
      acc[nt] = __builtin_amdgcn_mfma_f32_16x16x32_bf16(af, bo_[bofs + nt * 16], acc[nt], 0, 0, 0);
  }
#pragma unroll
  for (int nt = 0; nt < 8; ++nt)
#pragma unroll
    for (int r = 0; r < 4; ++r)
      out[(size_t)(t0w + g * 4 + r) * E_ + nt * 16 + c] = acc[nt][r];
}

// ------------------------------------------------------------------
extern "C" void kernel_launch(void* const* d_in, const int* in_sizes, int n_in,
                              void* d_out, int out_size, void* d_ws, size_t ws_size,
                              hipStream_t stream) {
  const float* xc_off  = (const float*)d_in[0];
  const float* zc_off  = (const float*)d_in[2];
  const float* zc_on   = (const float*)d_in[3];
  const float* latents = (const float*)d_in[4];
  const float* fake    = (const float*)d_in[5];
  const float* Wq      = (const float*)d_in[6];
  const float* Wk      = (const float*)d_in[7];
  const float* Wv      = (const float*)d_in[8];
  const float* Wo      = (const float*)d_in[9];
  const int*   ignore  = (const int*)d_in[10];

  float* out = (float*)d_out;

  // workspace layout
  float* Qp = (float*)d_ws;                                  // S*E fp32 (2 MB)
  unsigned short* Wsw = (unsigned short*)(Qp + (size_t)S_ * E_);  // 3x16384 bf16
  int* seg_arr = (int*)(Wsw + SWZ3);                         // NTOK
  int* cnt     = seg_arr + NTOK;                             // NCELL
  int* offs    = cnt + NCELL;                                // NCELL+1
  int* cursor  = offs + NCELL + 2;                           // NCELL
  int* sorted  = cursor + NCELL;                             // NTOK
  unsigned short* Wk_sw = Wsw;
  unsigned short* Wv_sw = Wsw + 16384;
  unsigned short* Wo_sw = Wsw + 32768;

  hipMemsetAsync(cnt, 0, NCELL * sizeof(int), stream);
  setup_kernel<<<48, 1024, 0, stream>>>(Wq, Wk, Wv, Wo, latents, xc_off,
                                        Wsw, Qp, seg_arr, cnt);
  scan_kernel<<<1, 1024, 0, stream>>>(cnt, offs, cursor);
  scatter_ids<<<NTOK / 256, 256, 0, stream>>>(seg_arr, cursor, sorted);
  fused_cells<<<FUSED_GRID, 1024, 0, stream>>>(zc_off, zc_on, fake, ignore,
                                               Wk_sw, Wv_sw, Qp, offs, sorted, out);
  finalize_mfma<<<NCELL / 128, 512, 0, stream>>>(Wo_sw, out);
}

// Round 7
// 241.310 us; speedup vs baseline: 1.2138x; 1.2138x over previous
//
#include <hip/hip_runtime.h>
#include <math.h>

namespace {
constexpr int B_  = 8;
constexpr int U_  = 16384;
constexpr int S_  = 4096;
constexpr int E_  = 128;
constexpr int NTOK  = B_ * U_;   // 131072
constexpr int NCELL = B_ * S_;   // 32768
constexpr int FUSED_GRID = 768;
constexpr int SWZ2 = 2 * 16384;  // Wv,Wo swizzle elements
}

typedef __attribute__((ext_vector_type(8))) short bf16x8;
typedef __attribute__((ext_vector_type(4))) float f32x4;

__device__ inline unsigned short bf16rne(float x) {
  unsigned u = __float_as_uint(x);
  u = u + 0x7fffu + ((u >> 16) & 1u);
  return (unsigned short)(u >> 16);
}

__device__ inline bf16x8 pack8(float4 a, float4 b) {
  bf16x8 r;
  r[0] = (short)bf16rne(a.x); r[1] = (short)bf16rne(a.y);
  r[2] = (short)bf16rne(a.z); r[3] = (short)bf16rne(a.w);
  r[4] = (short)bf16rne(b.x); r[5] = (short)bf16rne(b.y);
  r[6] = (short)bf16rne(b.z); r[7] = (short)bf16rne(b.w);
  return r;
}

// ------------------------------------------------------------------
// L1: wide setup launch.
//  blocks 0..15  : qproj -> Qp[s][d*8+h] = 0.25*(latents@Wq)[s][h*16+d]
//  blocks 16..47 : grid-stride { swizzle Wv/Wo -> bf16 B-frag, bucketize }
// ------------------------------------------------------------------
__global__ __launch_bounds__(1024, 4) void setup_kernel(
    const float* __restrict__ Wq, const float* __restrict__ Wv,
    const float* __restrict__ Wo,
    const float* __restrict__ latents, const float* __restrict__ xc_off,
    unsigned short* __restrict__ Wsw, float* __restrict__ Qp,
    int* __restrict__ seg_arr, int* __restrict__ cnt) {
  const int tid = threadIdx.x;

  if (blockIdx.x < 16) {
    __shared__ __align__(16) unsigned short wq[16384];
    for (int i = tid; i < 16384; i += 1024) {
      const int k = i >> 7, n = i & 127;
      wq[(((k >> 3) * 128 + n) << 3) + (k & 7)] = bf16rne(Wq[i]);
    }
    __syncthreads();

    const int wave = tid >> 6, lane = tid & 63;
    const int c = lane & 15, g = lane >> 4;
    const int t0w = blockIdx.x * 256 + wave * 16;

    f32x4 acc[8];
#pragma unroll
    for (int i = 0; i < 8; ++i) acc[i] = {0.f, 0.f, 0.f, 0.f};

    const float* arow = latents + (size_t)(t0w + c) * E_ + g * 8;
    const bf16x8* bq = (const bf16x8*)wq;
#pragma unroll
    for (int ks = 0; ks < 4; ++ks) {
      float4 a0 = *(const float4*)(arow + ks * 32);
      float4 a1 = *(const float4*)(arow + ks * 32 + 4);
      bf16x8 af = pack8(a0, a1);
      const int bo = (ks * 4 + g) * 128 + c;
#pragma unroll
      for (int nt = 0; nt < 8; ++nt)
        acc[nt] = __builtin_amdgcn_mfma_f32_16x16x32_bf16(af, bq[bo + nt * 16], acc[nt], 0, 0, 0);
    }
#pragma unroll
    for (int nt = 0; nt < 8; ++nt)
#pragma unroll
      for (int r = 0; r < 4; ++r)
        Qp[(size_t)(t0w + g * 4 + r) * E_ + c * 8 + nt] = acc[nt][r] * 0.25f;
  } else {
    const int base = (blockIdx.x - 16) * 1024 + tid;
    const int stride = 32 * 1024;
    for (int i = base; i < SWZ2 + NTOK; i += stride) {
      if (i < SWZ2) {
        const int w = i >> 14, e = i & 16383;
        const int k = e >> 7, n = e & 127;
        const float* src = (w == 0) ? Wv : Wo;
        Wsw[w * 16384 + (((k >> 3) * 128 + n) << 3) + (k & 7)] = bf16rne(src[e]);
      } else {
        const int tok = i - SWZ2;
        const int b = tok >> 14;
        // EXACT replication of reference fp32 bucketize math
        const float sp = 1.0f / 63.0f;
        const float half = sp * 0.5f;
        const float x0 = xc_off[(size_t)tok * 2 + 0];
        const float x1 = xc_off[(size_t)tok * 2 + 1];
        float n0 = floorf((x0 - 0.0f + half) / sp);
        float n1 = floorf((x1 - 0.0f + half) / sp);
        n0 = fminf(fmaxf(n0, 0.0f), 63.0f);
        n1 = fminf(fmaxf(n1, 0.0f), 63.0f);
        const int seg = b * S_ + (int)(n0 * 64.0f + n1);
        seg_arr[tok] = seg;
        atomicAdd(&cnt[seg], 1);
      }
    }
  }
}

// ------------------------------------------------------------------
// L2: per-cell QK table: QKt[s][e>>3][h][e&7] = bf16( sum_j Wk[e][h*16+j]*q_s[h*16+j] )
// Laid out so the fused score-MFMA B-frag is one 16B load:
//   addr = s*1024 + (ks*4+g)*64 + (c&7)*8 + j   (cols 8..15 duplicate 0..7, ignored)
// ------------------------------------------------------------------
__global__ __launch_bounds__(128) void qk_table(
    const float* __restrict__ Wk, const float* __restrict__ Qp,
    unsigned short* __restrict__ QKt) {
  const int s = blockIdx.x;
  const int e = threadIdx.x;
  __shared__ float qls[128];
  // Qp[s][i]: i = d*8+h holds q[h*16+d]  ->  qls[h*16+d]
  {
    const float v = Qp[(size_t)s * E_ + e];
    qls[(e & 7) * 16 + (e >> 3)] = v;
  }
  __syncthreads();

  const float* wrow = Wk + (size_t)e * E_;
  unsigned short* dst = QKt + (size_t)s * 1024 + (e >> 3) * 64 + (e & 7);
#pragma unroll
  for (int h = 0; h < 8; ++h) {
    float acc = 0.f;
#pragma unroll
    for (int j = 0; j < 16; ++j)
      acc = fmaf(wrow[h * 16 + j], qls[h * 16 + j], acc);
    dst[h * 8] = bf16rne(acc);
  }
}

// ------------------------------------------------------------------
// L3: exclusive scan of 32K counts (single block)
// ------------------------------------------------------------------
__global__ __launch_bounds__(1024) void scan_kernel(
    const int* __restrict__ cnt, int* __restrict__ offs, int* __restrict__ cursor) {
  __shared__ int sh[1024];
  const int tid = threadIdx.x;
  const int base = tid * 32;
  int local[32];
  int tot = 0;
#pragma unroll
  for (int i = 0; i < 32; ++i) { local[i] = cnt[base + i]; tot += local[i]; }
  sh[tid] = tot;
  __syncthreads();
  for (int ofs = 1; ofs < 1024; ofs <<= 1) {
    int v = (tid >= ofs) ? sh[tid - ofs] : 0;
    __syncthreads();
    sh[tid] += v;
    __syncthreads();
  }
  int run = sh[tid] - tot;
#pragma unroll
  for (int i = 0; i < 32; ++i) {
    offs[base + i] = run;
    cursor[base + i] = run;
    run += local[i];
  }
  if (tid == 1023) offs[NCELL] = run;
}

// ------------------------------------------------------------------
// L4: scatter token ids into sorted order
// ------------------------------------------------------------------
__global__ __launch_bounds__(256) void scatter_ids(
    const int* __restrict__ seg_arr, int* __restrict__ cursor,
    int* __restrict__ sorted) {
  const int tok = blockIdx.x * 256 + threadIdx.x;
  const int seg = seg_arr[tok];
  const int r = atomicAdd(&cursor[seg], 1);
  sorted[r] = tok;
}

// ------------------------------------------------------------------
// L5: fused per-cell kernel. One wave = one cell.
//   scores: S = Z @ QKt_s  (4 MFMAs, heads on N axis) -> exp on C-layout
//   lanes -> 512B per-wave LDS bounce (no barrier; wave-internal order).
//   V: per-head 4 MFMAs from LDS Wv; accumulate w*V; direct store.
// ------------------------------------------------------------------
__global__ __launch_bounds__(512, 4) void fused_cells(
    const float* __restrict__ zc_off, const float* __restrict__ zc_on,
    const float* __restrict__ fake, const int* __restrict__ ignore_flag,
    const unsigned short* __restrict__ Wv_sw,
    const unsigned short* __restrict__ QKt, const int* __restrict__ offs,
    const int* __restrict__ sorted, float* __restrict__ out) {
  __shared__ __align__(16) unsigned short wv[16384];
  __shared__ float wbuf[8][16][8];   // [wave][t][h]
  const int tid = threadIdx.x;
  {
    const uint4* sv = (const uint4*)Wv_sw;
    uint4* dv = (uint4*)wv;
#pragma unroll
    for (int i = 0; i < 4; ++i) dv[i * 512 + tid] = sv[i * 512 + tid];
  }
  const int ign = *ignore_flag;
  __syncthreads();

  const int wave = tid >> 6, lane = tid & 63;
  const int c = lane & 15, g = lane >> 4;
  const bf16x8* bv = (const bf16x8*)wv;

  for (int grp = blockIdx.x; grp < NCELL / 8; grp += FUSED_GRID) {
    const int cell = grp * 8 + wave;
    const int s = cell & (S_ - 1);
    const int base = offs[cell];
    const int n_off = offs[cell + 1] - base;
    const bf16x8* bqk = (const bf16x8*)(QKt + (size_t)s * 1024);

    float num_acc[8], den_acc[8];
#pragma unroll
    for (int i = 0; i < 8; ++i) { num_acc[i] = 0.f; den_acc[i] = 0.f; }

    const int chunks = (n_off + 16) >> 4;

    for (int ch = 0; ch < chunks; ++ch) {
      const int idx = ch * 16 + c;
      const float* arow;
      if (idx < n_off)       arow = zc_off + (size_t)sorted[base + idx] * E_;
      else if (idx == n_off) arow = ign ? fake : (zc_on + (size_t)cell * E_);
      else                   arow = zc_on;   // pad: weight forced to 0
      arow += g * 8;

      bf16x8 af[4];
#pragma unroll
      for (int ks = 0; ks < 4; ++ks) {
        float4 a0 = *(const float4*)(arow + ks * 32);
        float4 a1 = *(const float4*)(arow + ks * 32 + 4);
        af[ks] = pack8(a0, a1);
      }

      // scores: S[t, h] = z_t . qk_h  (4 MFMAs; cols 8..15 duplicates)
      f32x4 aS = {0.f, 0.f, 0.f, 0.f};
#pragma unroll
      for (int ks = 0; ks < 4; ++ks)
        aS = __builtin_amdgcn_mfma_f32_16x16x32_bf16(af[ks], bqk[(ks * 4 + g) * 8 + (c & 7)], aS, 0, 0, 0);

      if (c < 8) {
#pragma unroll
        for (int r = 0; r < 4; ++r) {
          const int t = g * 4 + r;
          wbuf[wave][t][c] = (ch * 16 + t <= n_off) ? __expf(aS[r]) : 0.f;
        }
      }
      // wave-internal ds_write -> ds_read ordering via compiler lgkmcnt

#pragma unroll 2
      for (int h = 0; h < 8; ++h) {
        float wr[4];
#pragma unroll
        for (int r = 0; r < 4; ++r) wr[r] = wbuf[wave][g * 4 + r][h];

        const int bo = g * 128 + c + h * 16;
        f32x4 aV = {0.f, 0.f, 0.f, 0.f};
#pragma unroll
        for (int ks = 0; ks < 4; ++ks)
          aV = __builtin_amdgcn_mfma_f32_16x16x32_bf16(af[ks], bv[bo + ks * 512], aV, 0, 0, 0);

        float sv = 0.f, sd = 0.f;
#pragma unroll
        for (int r = 0; r < 4; ++r) { sv = fmaf(wr[r], aV[r], sv); sd += wr[r]; }
        num_acc[h] += sv;
        den_acc[h] += sd;
      }
    }

#pragma unroll
    for (int i = 0; i < 8; ++i) {
      num_acc[i] += __shfl_xor(num_acc[i], 16, 64);
      num_acc[i] += __shfl_xor(num_acc[i], 32, 64);
      den_acc[i] += __shfl_xor(den_acc[i], 16, 64);
      den_acc[i] += __shfl_xor(den_acc[i], 32, 64);
    }
#pragma unroll
    for (int b = 0; b < 2; ++b) {
      const int nt = 2 * g + b;
      out[(size_t)cell * E_ + nt * 16 + c] = num_acc[nt] / den_acc[nt];
    }
  }
}

// ------------------------------------------------------------------
// L6: finalize in-place: out = out @ Wo
// ------------------------------------------------------------------
__global__ __launch_bounds__(512, 4) void finalize_mfma(
    const unsigned short* __restrict__ Wo_sw, float* __restrict__ out) {
  __shared__ __align__(16) unsigned short wo[16384];
  const int tid = threadIdx.x;
  {
    const uint4* s = (const uint4*)Wo_sw;
    uint4* d = (uint4*)wo;
#pragma unroll
    for (int i = 0; i < 4; ++i) d[i * 512 + tid] = s[i * 512 + tid];
  }
  __syncthreads();

  const int wave = tid >> 6, lane = tid & 63;
  const int c = lane & 15, g = lane >> 4;
  const int t0w = blockIdx.x * 128 + wave * 16;

  f32x4 acc[8];
#pragma unroll
  for (int i = 0; i < 8; ++i) acc[i] = {0.f, 0.f, 0.f, 0.f};

  const float* nrow = out + (size_t)(t0w + c) * E_ + g * 8;
  const bf16x8* bo_ = (const bf16x8*)wo;
#pragma unroll
  for (int ks = 0; ks < 4; ++ks) {
    float4 a0 = *(const float4*)(nrow + ks * 32);
    float4 a1 = *(const float4*)(nrow + ks * 32 + 4);
    bf16x8 af = pack8(a0, a1);
    const int bofs = (ks * 4 + g) * 128 + c;
#pragma unroll
    for (int nt = 0; nt < 8; ++nt)
      acc[nt] = __builtin_amdgcn_mfma_f32_16x16x32_bf16(af, bo_[bofs + nt * 16], acc[nt], 0, 0, 0);
  }
#pragma unroll
  for (int nt = 0; nt < 8; ++nt)
#pragma unroll
    for (int r = 0; r < 4; ++r)
      out[(size_t)(t0w + g * 4 + r) * E_ + nt * 16 + c] = acc[nt][r];
}

// ------------------------------------------------------------------
extern "C" void kernel_launch(void* const* d_in, const int* in_sizes, int n_in,
                              void* d_out, int out_size, void* d_ws, size_t ws_size,
                              hipStream_t stream) {
  const float* xc_off  = (const float*)d_in[0];
  const float* zc_off  = (const float*)d_in[2];
  const float* zc_on   = (const float*)d_in[3];
  const float* latents = (const float*)d_in[4];
  const float* fake    = (const float*)d_in[5];
  const float* Wq      = (const float*)d_in[6];
  const float* Wk      = (const float*)d_in[7];
  const float* Wv      = (const float*)d_in[8];
  const float* Wo      = (const float*)d_in[9];
  const int*   ignore  = (const int*)d_in[10];

  float* out = (float*)d_out;

  // workspace layout
  float* Qp = (float*)d_ws;                                  // S*E fp32 (2 MB)
  unsigned short* Wsw = (unsigned short*)(Qp + (size_t)S_ * E_);  // 2x16384 bf16
  unsigned short* QKt = Wsw + SWZ2;                          // S*1024 bf16 (8 MB)
  int* seg_arr = (int*)(QKt + (size_t)S_ * 1024);            // NTOK
  int* cnt     = seg_arr + NTOK;                             // NCELL
  int* offs    = cnt + NCELL;                                // NCELL+1
  int* cursor  = offs + NCELL + 2;                           // NCELL
  int* sorted  = cursor + NCELL;                             // NTOK
  unsigned short* Wv_sw = Wsw;
  unsigned short* Wo_sw = Wsw + 16384;

  hipMemsetAsync(cnt, 0, NCELL * sizeof(int), stream);
  setup_kernel<<<48, 1024, 0, stream>>>(Wq, Wv, Wo, latents, xc_off,
                                        Wsw, Qp, seg_arr, cnt);
  qk_table<<<S_, 128, 0, stream>>>(Wk, Qp, QKt);
  scan_kernel<<<1, 1024, 0, stream>>>(cnt, offs, cursor);
  scatter_ids<<<NTOK / 256, 256, 0, stream>>>(seg_arr, cursor, sorted);
  fused_cells<<<FUSED_GRID, 512, 0, stream>>>(zc_off, zc_on, fake, ignore,
                                              Wv_sw, QKt, offs, sorted, out);
  finalize_mfma<<<NCELL / 128, 512, 0, stream>>>(Wo_sw, out);
}

// Round 8
// 215.308 us; speedup vs baseline: 1.3604x; 1.1208x over previous
//
#include <hip/hip_runtime.h>
#include <hip/hip_bf16.h>
#include <math.h>

namespace {
constexpr int B_  = 8;
constexpr int U_  = 16384;
constexpr int S_  = 4096;
constexpr int E_  = 128;
constexpr int NTOK  = B_ * U_;   // 131072
constexpr int NCELL = B_ * S_;   // 32768
constexpr int FUSED_GRID = 768;  // 3 blocks/CU
constexpr int CAP = 32;          // max off-grid tokens per cell (Poisson λ~4.1)
constexpr int SWZ2 = 2 * 16384;  // Wv,Wo swizzle elements
}

typedef __attribute__((ext_vector_type(8))) short bf16x8;
typedef __attribute__((ext_vector_type(4))) float f32x4;

__device__ inline unsigned short bf16rne(float x) {
  unsigned u = __float_as_uint(x);
  u = u + 0x7fffu + ((u >> 16) & 1u);
  return (unsigned short)(u >> 16);
}

__device__ inline bf16x8 pack8(float4 a, float4 b) {
  union { __hip_bfloat162 h; unsigned int u; } q0, q1, q2, q3;
  q0.h = __float22bfloat162_rn(make_float2(a.x, a.y));
  q1.h = __float22bfloat162_rn(make_float2(a.z, a.w));
  q2.h = __float22bfloat162_rn(make_float2(b.x, b.y));
  q3.h = __float22bfloat162_rn(make_float2(b.z, b.w));
  union { unsigned int u[4]; bf16x8 v; } r;
  r.u[0] = q0.u; r.u[1] = q1.u; r.u[2] = q2.u; r.u[3] = q3.u;
  return r.v;
}

// ------------------------------------------------------------------
// L1: wide setup launch (256 blocks).
//  blocks 0..15  : qproj -> Qp[s][d*8+h] = 0.25*(latents@Wq)[s][h*16+d]
//  blocks 16..255: grid-stride { swizzle Wv/Wo -> bf16 B-frag,
//                                bucketize + DIRECT scatter into CAP slots }
// ------------------------------------------------------------------
__global__ __launch_bounds__(1024, 4) void setup_kernel(
    const float* __restrict__ Wq, const float* __restrict__ Wv,
    const float* __restrict__ Wo,
    const float* __restrict__ latents, const float* __restrict__ xc_off,
    unsigned short* __restrict__ Wsw, float* __restrict__ Qp,
    int* __restrict__ cnt, int* __restrict__ sorted) {
  const int tid = threadIdx.x;

  if (blockIdx.x < 16) {
    __shared__ __align__(16) unsigned short wq[16384];
    for (int i = tid; i < 16384; i += 1024) {
      const int k = i >> 7, n = i & 127;
      wq[(((k >> 3) * 128 + n) << 3) + (k & 7)] = bf16rne(Wq[i]);
    }
    __syncthreads();

    const int wave = tid >> 6, lane = tid & 63;
    const int c = lane & 15, g = lane >> 4;
    const int t0w = blockIdx.x * 256 + wave * 16;

    f32x4 acc[8];
#pragma unroll
    for (int i = 0; i < 8; ++i) acc[i] = {0.f, 0.f, 0.f, 0.f};

    const float* arow = latents + (size_t)(t0w + c) * E_ + g * 8;
    const bf16x8* bq = (const bf16x8*)wq;
#pragma unroll
    for (int ks = 0; ks < 4; ++ks) {
      float4 a0 = *(const float4*)(arow + ks * 32);
      float4 a1 = *(const float4*)(arow + ks * 32 + 4);
      bf16x8 af = pack8(a0, a1);
      const int bo = (ks * 4 + g) * 128 + c;
#pragma unroll
      for (int nt = 0; nt < 8; ++nt)
        acc[nt] = __builtin_amdgcn_mfma_f32_16x16x32_bf16(af, bq[bo + nt * 16], acc[nt], 0, 0, 0);
    }
#pragma unroll
    for (int nt = 0; nt < 8; ++nt)
#pragma unroll
      for (int r = 0; r < 4; ++r)
        Qp[(size_t)(t0w + g * 4 + r) * E_ + c * 8 + nt] = acc[nt][r] * 0.25f;
  } else {
    const int base = (blockIdx.x - 16) * 1024 + tid;
    const int stride = 240 * 1024;
    for (int i = base; i < SWZ2 + NTOK; i += stride) {
      if (i < SWZ2) {
        const int w = i >> 14, e = i & 16383;
        const int k = e >> 7, n = e & 127;
        const float* src = (w == 0) ? Wv : Wo;
        Wsw[w * 16384 + (((k >> 3) * 128 + n) << 3) + (k & 7)] = bf16rne(src[e]);
      } else {
        const int tok = i - SWZ2;
        const int b = tok >> 14;
        // EXACT replication of reference fp32 bucketize math
        const float sp = 1.0f / 63.0f;
        const float half = sp * 0.5f;
        const float x0 = xc_off[(size_t)tok * 2 + 0];
        const float x1 = xc_off[(size_t)tok * 2 + 1];
        float n0 = floorf((x0 - 0.0f + half) / sp);
        float n1 = floorf((x1 - 0.0f + half) / sp);
        n0 = fminf(fmaxf(n0, 0.0f), 63.0f);
        n1 = fminf(fmaxf(n1, 0.0f), 63.0f);
        const int seg = b * S_ + (int)(n0 * 64.0f + n1);
        const int rank = atomicAdd(&cnt[seg], 1);
        if (rank < CAP) sorted[seg * CAP + rank] = tok;
      }
    }
  }
}

// ------------------------------------------------------------------
// L2: per-cell QK table, 16 cells/block.
// QKt[s][e>>3][h][e&7] = bf16( sum_j Wk[e][h*16+j] * q_s[h*16+j] )
// Wk staged once per block in conflict-free padded LDS.
// ------------------------------------------------------------------
__global__ __launch_bounds__(256) void qk_table(
    const float* __restrict__ Wk, const float* __restrict__ Qp,
    unsigned short* __restrict__ QKt) {
  __shared__ float wkl[128 * 129];
  __shared__ float qls[16 * 128];
  const int tid = threadIdx.x;
  const int s0 = blockIdx.x * 16;

  for (int i = tid; i < 16384; i += 256)
    wkl[(i >> 7) * 129 + (i & 127)] = Wk[i];
  for (int i = tid; i < 2048; i += 256) {
    const int sl = i >> 7, idx = i & 127;     // idx = d*8+h
    qls[sl * 128 + (idx & 7) * 16 + (idx >> 3)] = Qp[(size_t)(s0 + sl) * E_ + idx];
  }
  __syncthreads();

  const int e = tid & 127, half = tid >> 7;
#pragma unroll
  for (int h = 0; h < 8; ++h) {
    float wr[16];
#pragma unroll
    for (int j = 0; j < 16; ++j) wr[j] = wkl[e * 129 + h * 16 + j];
#pragma unroll
    for (int cl = 0; cl < 8; ++cl) {
      const int sl = half * 8 + cl;
      float acc = 0.f;
#pragma unroll
      for (int j = 0; j < 16; ++j)
        acc = fmaf(wr[j], qls[sl * 128 + h * 16 + j], acc);
      QKt[(size_t)(s0 + sl) * 1024 + (e >> 3) * 64 + h * 8 + (e & 7)] = bf16rne(acc);
    }
  }
}

// ------------------------------------------------------------------
// L3: fused per-cell kernel. One wave = one cell.
//   scores: S = Z @ QKt_s (4 MFMAs, heads on N) -> exp -> padded LDS bounce
//   V: per-head 4 MFMAs from LDS Wv; accumulate w*V; direct store.
// ------------------------------------------------------------------
__global__ __launch_bounds__(512, 6) void fused_cells(
    const float* __restrict__ zc_off, const float* __restrict__ zc_on,
    const float* __restrict__ fake, const int* __restrict__ ignore_flag,
    const unsigned short* __restrict__ Wv_sw,
    const unsigned short* __restrict__ QKt, const int* __restrict__ cnt,
    const int* __restrict__ sorted, float* __restrict__ out) {
  __shared__ __align__(16) unsigned short wv[16384];
  __shared__ float wbuf[8][16][9];   // [wave][t][h], padded: conflict-free
  const int tid = threadIdx.x;
  {
    const uint4* sv = (const uint4*)Wv_sw;
    uint4* dv = (uint4*)wv;
#pragma unroll
    for (int i = 0; i < 4; ++i) dv[i * 512 + tid] = sv[i * 512 + tid];
  }
  const int ign = *ignore_flag;
  __syncthreads();

  const int wave = tid >> 6, lane = tid & 63;
  const int c = lane & 15, g = lane >> 4;
  const bf16x8* bv = (const bf16x8*)wv;

  for (int grp = blockIdx.x; grp < NCELL / 8; grp += FUSED_GRID) {
    const int cell = grp * 8 + wave;
    const int s = cell & (S_ - 1);
    const int base = cell * CAP;
    const int n_off = min(cnt[cell], CAP);
    const bf16x8* bqk = (const bf16x8*)(QKt + (size_t)s * 1024);

    float num_acc[8], den_acc[8];
#pragma unroll
    for (int i = 0; i < 8; ++i) { num_acc[i] = 0.f; den_acc[i] = 0.f; }

    const int chunks = (n_off + 16) >> 4;

    for (int ch = 0; ch < chunks; ++ch) {
      const int idx = ch * 16 + c;
      const float* arow;
      if (idx < n_off)       arow = zc_off + (size_t)sorted[base + idx] * E_;
      else if (idx == n_off) arow = ign ? fake : (zc_on + (size_t)cell * E_);
      else                   arow = zc_on;   // pad: weight forced to 0
      arow += g * 8;

      bf16x8 af[4];
#pragma unroll
      for (int ks = 0; ks < 4; ++ks) {
        float4 a0 = *(const float4*)(arow + ks * 32);
        float4 a1 = *(const float4*)(arow + ks * 32 + 4);
        af[ks] = pack8(a0, a1);
      }

      // scores: S[t, h] = z_t . qk_h  (4 MFMAs; n-cols 8..15 duplicate 0..7)
      f32x4 aS = {0.f, 0.f, 0.f, 0.f};
#pragma unroll
      for (int ks = 0; ks < 4; ++ks)
        aS = __builtin_amdgcn_mfma_f32_16x16x32_bf16(af[ks], bqk[(ks * 4 + g) * 8 + (c & 7)], aS, 0, 0, 0);

      if (c < 8) {
#pragma unroll
        for (int r = 0; r < 4; ++r) {
          const int t = g * 4 + r;
          wbuf[wave][t][c] = (ch * 16 + t <= n_off) ? __expf(aS[r]) : 0.f;
        }
      }
      // wave-internal ds_write -> ds_read ordering via compiler lgkmcnt

#pragma unroll 2
      for (int h = 0; h < 8; ++h) {
        float wr[4];
#pragma unroll
        for (int r = 0; r < 4; ++r) wr[r] = wbuf[wave][g * 4 + r][h];

        const int bo = g * 128 + c + h * 16;
        f32x4 aV = {0.f, 0.f, 0.f, 0.f};
#pragma unroll
        for (int ks = 0; ks < 4; ++ks)
          aV = __builtin_amdgcn_mfma_f32_16x16x32_bf16(af[ks], bv[bo + ks * 512], aV, 0, 0, 0);

        float sv = 0.f, sd = 0.f;
#pragma unroll
        for (int r = 0; r < 4; ++r) { sv = fmaf(wr[r], aV[r], sv); sd += wr[r]; }
        num_acc[h] += sv;
        den_acc[h] += sd;
      }
    }

#pragma unroll
    for (int i = 0; i < 8; ++i) {
      num_acc[i] += __shfl_xor(num_acc[i], 16, 64);
      num_acc[i] += __shfl_xor(num_acc[i], 32, 64);
      den_acc[i] += __shfl_xor(den_acc[i], 16, 64);
      den_acc[i] += __shfl_xor(den_acc[i], 32, 64);
    }
#pragma unroll
    for (int b = 0; b < 2; ++b) {
      const int nt = 2 * g + b;
      out[(size_t)cell * E_ + nt * 16 + c] = num_acc[nt] / den_acc[nt];
    }
  }
}

// ------------------------------------------------------------------
// L4: finalize in-place: out = out @ Wo
// ------------------------------------------------------------------
__global__ __launch_bounds__(512, 4) void finalize_mfma(
    const unsigned short* __restrict__ Wo_sw, float* __restrict__ out) {
  __shared__ __align__(16) unsigned short wo[16384];
  const int tid = threadIdx.x;
  {
    const uint4* s = (const uint4*)Wo_sw;
    uint4* d = (uint4*)wo;
#pragma unroll
    for (int i = 0; i < 4; ++i) d[i * 512 + tid] = s[i * 512 + tid];
  }
  __syncthreads();

  const int wave = tid >> 6, lane = tid & 63;
  const int c = lane & 15, g = lane >> 4;
  const int t0w = blockIdx.x * 128 + wave * 16;

  f32x4 acc[8];
#pragma unroll
  for (int i = 0; i < 8; ++i) acc[i] = {0.f, 0.f, 0.f, 0.f};

  const float* nrow = out + (size_t)(t0w + c) * E_ + g * 8;
  const bf16x8* bo_ = (const bf16x8*)wo;
#pragma unroll
  for (int ks = 0; ks < 4; ++ks) {
    float4 a0 = *(const float4*)(nrow + ks * 32);
    float4 a1 = *(const float4*)(nrow + ks * 32 + 4);
    bf16x8 af = pack8(a0, a1);
    const int bofs = (ks * 4 + g) * 128 + c;
#pragma unroll
    for (int nt = 0; nt < 8; ++nt)
      acc[nt] = __builtin_amdgcn_mfma_f32_16x16x32_bf16(af, bo_[bofs + nt * 16], acc[nt], 0, 0, 0);
  }
#pragma unroll
  for (int nt = 0; nt < 8; ++nt)
#pragma unroll
    for (int r = 0; r < 4; ++r)
      out[(size_t)(t0w + g * 4 + r) * E_ + nt * 16 + c] = acc[nt][r];
}

// ------------------------------------------------------------------
extern "C" void kernel_launch(void* const* d_in, const int* in_sizes, int n_in,
                              void* d_out, int out_size, void* d_ws, size_t ws_size,
                              hipStream_t stream) {
  const float* xc_off  = (const float*)d_in[0];
  const float* zc_off  = (const float*)d_in[2];
  const float* zc_on   = (const float*)d_in[3];
  const float* latents = (const float*)d_in[4];
  const float* fake    = (const float*)d_in[5];
  const float* Wq      = (const float*)d_in[6];
  const float* Wk      = (const float*)d_in[7];
  const float* Wv      = (const float*)d_in[8];
  const float* Wo      = (const float*)d_in[9];
  const int*   ignore  = (const int*)d_in[10];

  float* out = (float*)d_out;

  // workspace layout (~14.2 MB)
  float* Qp = (float*)d_ws;                                  // S*E fp32 (2 MB)
  unsigned short* Wsw = (unsigned short*)(Qp + (size_t)S_ * E_);  // Wv,Wo bf16 (64 KB)
  unsigned short* QKt = Wsw + SWZ2;                          // S*1024 bf16 (8 MB)
  int* cnt    = (int*)(QKt + (size_t)S_ * 1024);             // NCELL (128 KB)
  int* sorted = cnt + NCELL;                                 // NCELL*CAP (4 MB)
  unsigned short* Wv_sw = Wsw;
  unsigned short* Wo_sw = Wsw + 16384;

  hipMemsetAsync(cnt, 0, NCELL * sizeof(int), stream);
  setup_kernel<<<256, 1024, 0, stream>>>(Wq, Wv, Wo, latents, xc_off,
                                         Wsw, Qp, cnt, sorted);
  qk_table<<<S_ / 16, 256, 0, stream>>>(Wk, Qp, QKt);
  fused_cells<<<FUSED_GRID, 512, 0, stream>>>(zc_off, zc_on, fake, ignore,
                                              Wv_sw, QKt, cnt, sorted, out);
  finalize_mfma<<<NCELL / 128, 512, 0, stream>>>(Wo_sw, out);
}

// Round 9
// 186.533 us; speedup vs baseline: 1.5702x; 1.1543x over previous
//
#include <hip/hip_runtime.h>
#include <hip/hip_bf16.h>
#include <math.h>

namespace {
constexpr int B_  = 8;
constexpr int U_  = 16384;
constexpr int S_  = 4096;
constexpr int E_  = 128;
constexpr int NTOK  = B_ * U_;   // 131072
constexpr int NCELL = B_ * S_;   // 32768
constexpr int FUSED_GRID = 1024; // 4 blocks/CU
constexpr int CAP = 32;          // max off-grid tokens per cell (Poisson λ~4.1)
constexpr int SWZ2 = 2 * 16384;  // Wv,Wo swizzle elements
}

typedef __attribute__((ext_vector_type(8))) short bf16x8;
typedef __attribute__((ext_vector_type(4))) float f32x4;

__device__ inline unsigned short bf16rne(float x) {
  unsigned u = __float_as_uint(x);
  u = u + 0x7fffu + ((u >> 16) & 1u);
  return (unsigned short)(u >> 16);
}

__device__ inline bf16x8 pack8(float4 a, float4 b) {
  union { __hip_bfloat162 h; unsigned int u; } q0, q1, q2, q3;
  q0.h = __float22bfloat162_rn(make_float2(a.x, a.y));
  q1.h = __float22bfloat162_rn(make_float2(a.z, a.w));
  q2.h = __float22bfloat162_rn(make_float2(b.x, b.y));
  q3.h = __float22bfloat162_rn(make_float2(b.z, b.w));
  union { unsigned int u[4]; bf16x8 v; } r;
  r.u[0] = q0.u; r.u[1] = q1.u; r.u[2] = q2.u; r.u[3] = q3.u;
  return r.v;
}

// ------------------------------------------------------------------
// L1: single setup launch (256 blocks x 1024).
//  blocks 0..127  : own 32 cells each: qproj MFMA (waves 0-1) -> LDS qbuf,
//                   then all waves compute QKt for those cells.
//                   QKt[s][(e>>3)*64 + h*8 + (e&7)] = bf16(0.25*q_s . Wk-col)
//  blocks 128..255: swizzle Wv/Wo -> bf16 B-frag; bucketize + CAP-scatter.
// ------------------------------------------------------------------
__global__ __launch_bounds__(1024, 4) void setup_kernel(
    const float* __restrict__ Wq, const float* __restrict__ Wk,
    const float* __restrict__ Wv, const float* __restrict__ Wo,
    const float* __restrict__ latents, const float* __restrict__ xc_off,
    unsigned short* __restrict__ Wsw, unsigned short* __restrict__ QKt,
    int* __restrict__ cnt, int* __restrict__ sorted) {
  const int tid = threadIdx.x;

  if (blockIdx.x < 128) {
    __shared__ __align__(16) unsigned short wq[16384];  // 32 KB, B-frag swizzled
    __shared__ float wkt[128 * 129];                    // 66 KB, wkt[j*129+e]=Wk[e][j]
    __shared__ float qbuf[32 * 128];                    // 16 KB, qbuf[sl*128+n]=q_sl[n]
    const int s0 = blockIdx.x * 32;

    for (int i = tid; i < 16384; i += 1024) {
      const int k = i >> 7, n = i & 127;
      wq[(((k >> 3) * 128 + n) << 3) + (k & 7)] = bf16rne(Wq[i]);
      wkt[(i & 127) * 129 + (i >> 7)] = Wk[i];
    }
    __syncthreads();

    const int wave = tid >> 6, lane = tid & 63;
    const int c = lane & 15, g = lane >> 4;
    if (wave < 2) {
      const int t0w = s0 + wave * 16;
      f32x4 acc[8];
#pragma unroll
      for (int i = 0; i < 8; ++i) acc[i] = {0.f, 0.f, 0.f, 0.f};
      const float* arow = latents + (size_t)(t0w + c) * E_ + g * 8;
      const bf16x8* bq = (const bf16x8*)wq;
#pragma unroll
      for (int ks = 0; ks < 4; ++ks) {
        float4 a0 = *(const float4*)(arow + ks * 32);
        float4 a1 = *(const float4*)(arow + ks * 32 + 4);
        bf16x8 af = pack8(a0, a1);
        const int bo = (ks * 4 + g) * 128 + c;
#pragma unroll
        for (int nt = 0; nt < 8; ++nt)
          acc[nt] = __builtin_amdgcn_mfma_f32_16x16x32_bf16(af, bq[bo + nt * 16], acc[nt], 0, 0, 0);
      }
#pragma unroll
      for (int nt = 0; nt < 8; ++nt)
#pragma unroll
        for (int r = 0; r < 4; ++r)
          qbuf[(wave * 16 + g * 4 + r) * 128 + nt * 16 + c] = acc[nt][r] * 0.25f;
    }
    __syncthreads();

    // QKt: 32 cells x 128 e x 8 h; o = ((sl*8+h)*128+e)
#pragma unroll
    for (int k = 0; k < 32; ++k) {
      const int o = k * 1024 + tid;
      const int e = o & 127, h = (o >> 7) & 7, sl = o >> 10;
      float acc = 0.f;
#pragma unroll
      for (int j = 0; j < 16; ++j)
        acc = fmaf(wkt[(h * 16 + j) * 129 + e], qbuf[sl * 128 + h * 16 + j], acc);
      QKt[(size_t)(s0 + sl) * 1024 + (e >> 3) * 64 + h * 8 + (e & 7)] = bf16rne(acc);
    }
  } else {
    const int base = (blockIdx.x - 128) * 1024 + tid;
    const int stride = 128 * 1024;
    for (int i = base; i < SWZ2 + NTOK; i += stride) {
      if (i < SWZ2) {
        const int w = i >> 14, e = i & 16383;
        const int k = e >> 7, n = e & 127;
        const float* src = (w == 0) ? Wv : Wo;
        Wsw[w * 16384 + (((k >> 3) * 128 + n) << 3) + (k & 7)] = bf16rne(src[e]);
      } else {
        const int tok = i - SWZ2;
        const int b = tok >> 14;
        // EXACT replication of reference fp32 bucketize math
        const float sp = 1.0f / 63.0f;
        const float half = sp * 0.5f;
        const float x0 = xc_off[(size_t)tok * 2 + 0];
        const float x1 = xc_off[(size_t)tok * 2 + 1];
        float n0 = floorf((x0 - 0.0f + half) / sp);
        float n1 = floorf((x1 - 0.0f + half) / sp);
        n0 = fminf(fmaxf(n0, 0.0f), 63.0f);
        n1 = fminf(fmaxf(n1, 0.0f), 63.0f);
        const int seg = b * S_ + (int)(n0 * 64.0f + n1);
        const int rank = atomicAdd(&cnt[seg], 1);
        if (rank < CAP) sorted[seg * CAP + rank] = tok;
      }
    }
  }
}

// ------------------------------------------------------------------
// L2: fused per-cell kernel. One wave = one cell. (512,4): NO spill.
//   scores: S = Z @ QKt_s (4 MFMAs, heads on N) -> exp -> padded LDS bounce
//   V: per-head 4 MFMAs from LDS Wv; accumulate w*V; direct store.
// ------------------------------------------------------------------
__global__ __launch_bounds__(512, 4) void fused_cells(
    const float* __restrict__ zc_off, const float* __restrict__ zc_on,
    const float* __restrict__ fake, const int* __restrict__ ignore_flag,
    const unsigned short* __restrict__ Wv_sw,
    const unsigned short* __restrict__ QKt, const int* __restrict__ cnt,
    const int* __restrict__ sorted, float* __restrict__ out) {
  __shared__ __align__(16) unsigned short wv[16384];
  __shared__ float wbuf[8][16][9];   // [wave][t][h], padded
  const int tid = threadIdx.x;
  {
    const uint4* sv = (const uint4*)Wv_sw;
    uint4* dv = (uint4*)wv;
#pragma unroll
    for (int i = 0; i < 4; ++i) dv[i * 512 + tid] = sv[i * 512 + tid];
  }
  const int ign = *ignore_flag;
  __syncthreads();

  const int wave = tid >> 6, lane = tid & 63;
  const int c = lane & 15, g = lane >> 4;
  const bf16x8* bv = (const bf16x8*)wv;

  for (int grp = blockIdx.x; grp < NCELL / 8; grp += FUSED_GRID) {
    const int cell = grp * 8 + wave;
    const int s = cell & (S_ - 1);
    const int base = cell * CAP;
    const int n_off = min(cnt[cell], CAP);
    const bf16x8* bqk = (const bf16x8*)(QKt + (size_t)s * 1024);

    float num_acc[8], den_acc[8];
#pragma unroll
    for (int i = 0; i < 8; ++i) { num_acc[i] = 0.f; den_acc[i] = 0.f; }

    const int chunks = (n_off + 16) >> 4;

    for (int ch = 0; ch < chunks; ++ch) {
      const int idx = ch * 16 + c;
      const float* arow;
      if (idx < n_off)       arow = zc_off + (size_t)sorted[base + idx] * E_;
      else if (idx == n_off) arow = ign ? fake : (zc_on + (size_t)cell * E_);
      else                   arow = zc_on;   // pad: weight forced to 0
      arow += g * 8;

      bf16x8 af[4];
#pragma unroll
      for (int ks = 0; ks < 4; ++ks) {
        float4 a0 = *(const float4*)(arow + ks * 32);
        float4 a1 = *(const float4*)(arow + ks * 32 + 4);
        af[ks] = pack8(a0, a1);
      }

      // scores: S[t, h] = z_t . qk_h  (4 MFMAs; n-cols 8..15 duplicate 0..7)
      f32x4 aS = {0.f, 0.f, 0.f, 0.f};
#pragma unroll
      for (int ks = 0; ks < 4; ++ks)
        aS = __builtin_amdgcn_mfma_f32_16x16x32_bf16(af[ks], bqk[(ks * 4 + g) * 8 + (c & 7)], aS, 0, 0, 0);

      if (c < 8) {
#pragma unroll
        for (int r = 0; r < 4; ++r) {
          const int t = g * 4 + r;
          wbuf[wave][t][c] = (ch * 16 + t <= n_off) ? __expf(aS[r]) : 0.f;
        }
      }
      // wave-internal ds_write -> ds_read ordering via compiler lgkmcnt

#pragma unroll 2
      for (int h = 0; h < 8; ++h) {
        float wr[4];
#pragma unroll
        for (int r = 0; r < 4; ++r) wr[r] = wbuf[wave][g * 4 + r][h];

        const int bo = g * 128 + c + h * 16;
        f32x4 aV = {0.f, 0.f, 0.f, 0.f};
#pragma unroll
        for (int ks = 0; ks < 4; ++ks)
          aV = __builtin_amdgcn_mfma_f32_16x16x32_bf16(af[ks], bv[bo + ks * 512], aV, 0, 0, 0);

        float sv = 0.f, sd = 0.f;
#pragma unroll
        for (int r = 0; r < 4; ++r) { sv = fmaf(wr[r], aV[r], sv); sd += wr[r]; }
        num_acc[h] += sv;
        den_acc[h] += sd;
      }
    }

#pragma unroll
    for (int i = 0; i < 8; ++i) {
      num_acc[i] += __shfl_xor(num_acc[i], 16, 64);
      num_acc[i] += __shfl_xor(num_acc[i], 32, 64);
      den_acc[i] += __shfl_xor(den_acc[i], 16, 64);
      den_acc[i] += __shfl_xor(den_acc[i], 32, 64);
    }
#pragma unroll
    for (int b = 0; b < 2; ++b) {
      const int nt = 2 * g + b;
      out[(size_t)cell * E_ + nt * 16 + c] = num_acc[nt] / den_acc[nt];
    }
  }
}

// ------------------------------------------------------------------
// L3: finalize in-place: out = out @ Wo
// ------------------------------------------------------------------
__global__ __launch_bounds__(512, 4) void finalize_mfma(
    const unsigned short* __restrict__ Wo_sw, float* __restrict__ out) {
  __shared__ __align__(16) unsigned short wo[16384];
  const int tid = threadIdx.x;
  {
    const uint4* s = (const uint4*)Wo_sw;
    uint4* d = (uint4*)wo;
#pragma unroll
    for (int i = 0; i < 4; ++i) d[i * 512 + tid] = s[i * 512 + tid];
  }
  __syncthreads();

  const int wave = tid >> 6, lane = tid & 63;
  const int c = lane & 15, g = lane >> 4;
  const int t0w = blockIdx.x * 128 + wave * 16;

  f32x4 acc[8];
#pragma unroll
  for (int i = 0; i < 8; ++i) acc[i] = {0.f, 0.f, 0.f, 0.f};

  const float* nrow = out + (size_t)(t0w + c) * E_ + g * 8;
  const bf16x8* bo_ = (const bf16x8*)wo;
#pragma unroll
  for (int ks = 0; ks < 4; ++ks) {
    float4 a0 = *(const float4*)(nrow + ks * 32);
    float4 a1 = *(const float4*)(nrow + ks * 32 + 4);
    bf16x8 af = pack8(a0, a1);
    const int bofs = (ks * 4 + g) * 128 + c;
#pragma unroll
    for (int nt = 0; nt < 8; ++nt)
      acc[nt] = __builtin_amdgcn_mfma_f32_16x16x32_bf16(af, bo_[bofs + nt * 16], acc[nt], 0, 0, 0);
  }
#pragma unroll
  for (int nt = 0; nt < 8; ++nt)
#pragma unroll
    for (int r = 0; r < 4; ++r)
      out[(size_t)(t0w + g * 4 + r) * E_ + nt * 16 + c] = acc[nt][r];
}

// ------------------------------------------------------------------
extern "C" void kernel_launch(void* const* d_in, const int* in_sizes, int n_in,
                              void* d_out, int out_size, void* d_ws, size_t ws_size,
                              hipStream_t stream) {
  const float* xc_off  = (const float*)d_in[0];
  const float* zc_off  = (const float*)d_in[2];
  const float* zc_on   = (const float*)d_in[3];
  const float* latents = (const float*)d_in[4];
  const float* fake    = (const float*)d_in[5];
  const float* Wq      = (const float*)d_in[6];
  const float* Wk      = (const float*)d_in[7];
  const float* Wv      = (const float*)d_in[8];
  const float* Wo      = (const float*)d_in[9];
  const int*   ignore  = (const int*)d_in[10];

  float* out = (float*)d_out;

  // workspace layout (~12.2 MB)
  unsigned short* QKt = (unsigned short*)d_ws;               // S*1024 bf16 (8 MB)
  unsigned short* Wsw = QKt + (size_t)S_ * 1024;             // Wv,Wo bf16 (64 KB)
  int* cnt    = (int*)(Wsw + SWZ2);                          // NCELL (128 KB)
  int* sorted = cnt + NCELL;                                 // NCELL*CAP (4 MB)
  unsigned short* Wv_sw = Wsw;
  unsigned short* Wo_sw = Wsw + 16384;

  hipMemsetAsync(cnt, 0, NCELL * sizeof(int), stream);
  setup_kernel<<<256, 1024, 0, stream>>>(Wq, Wk, Wv, Wo, latents, xc_off,
                                         Wsw, QKt, cnt, sorted);
  fused_cells<<<FUSED_GRID, 512, 0, stream>>>(zc_off, zc_on, fake, ignore,
                                              Wv_sw, QKt, cnt, sorted, out);
  finalize_mfma<<<NCELL / 128, 512, 0, stream>>>(Wo_sw, out);
}